// Round 4
// baseline (180.776 us; speedup 1.0000x reference)
//
#include <hip/hip_runtime.h>

#define N_PY 512
#define IN_F 6
#define OUT_F 64
#define N_CELLS (512 * 512)
#define BN_EPS 1e-5

// ---------------------------------------------------------------------------
// ws layout (sorted path):
//   [0, 108)            : 27 floats — moment accumulators
//   [512, 2048)         : float Wp[64*6], float bp[64] — BN-folded params
//   [4096, +1MB)        : int hist[N_CELLS]   — per-cell point count
//   [+1MB, +2MB)        : int base[N_CELLS]   — intra-scanblock exclusive scan,
//                                               mutated to "local end" by scatter
//   [+2MB, +2MB+4K)     : int bsums[256]      — per-scanblock offsets (exclusive)
//   [+2MB+4K, +24MB...) : float sorted_x[n*6] — cell-sorted point rows
// fallback path reuses [4096...) as head[N_CELLS] + nxt[n].
// ---------------------------------------------------------------------------

__global__ void __launch_bounds__(256)
pfn_stats_hist_kernel(const float* __restrict__ x, const int* __restrict__ idx,
                      int n, float* __restrict__ acc, int* __restrict__ hist) {
    const int tid = blockIdx.x * blockDim.x + threadIdx.x;
    const int stride = gridDim.x * blockDim.x;
    const int npairs = n >> 1;

    float s[27];
#pragma unroll
    for (int k = 0; k < 27; ++k) s[k] = 0.f;

    for (int q = tid; q < npairs; q += stride) {
        const float4* base4 = (const float4*)(x + (size_t)q * 12);
        const float4 a = base4[0];
        const float4 b4 = base4[1];
        const float4 c4 = base4[2];
        const float p0[6] = {a.x, a.y, a.z, a.w, b4.x, b4.y};
        const float p1[6] = {b4.z, b4.w, c4.x, c4.y, c4.z, c4.w};
#pragma unroll
        for (int j = 0; j < 6; ++j) s[j] += p0[j] + p1[j];
        int k = 6;
#pragma unroll
        for (int i = 0; i < 6; ++i)
#pragma unroll
            for (int j = i; j < 6; ++j) {
                s[k] += p0[i] * p0[j] + p1[i] * p1[j];
                ++k;
            }
    }
    if ((n & 1) && tid == 0) {
        const float* p = x + (size_t)(n - 1) * 6;
        float v[6];
#pragma unroll
        for (int j = 0; j < 6; ++j) v[j] = p[j];
#pragma unroll
        for (int j = 0; j < 6; ++j) s[j] += v[j];
        int k = 6;
#pragma unroll
        for (int i = 0; i < 6; ++i)
#pragma unroll
            for (int j = i; j < 6; ++j) { s[k] += v[i] * v[j]; ++k; }
    }

    // histogram: per-point atomicAdd on L2-resident 1MB array
    for (int p = tid; p < n; p += stride) {
        const int2 ij = ((const int2*)idx)[p];
        atomicAdd(&hist[ij.x * N_PY + ij.y], 1);
    }

#pragma unroll
    for (int off = 32; off > 0; off >>= 1)
#pragma unroll
        for (int k = 0; k < 27; ++k) s[k] += __shfl_down(s[k], off, 64);

    __shared__ float lds[4][27];
    const int wid = threadIdx.x >> 6;
    const int lane = threadIdx.x & 63;
    if (lane == 0)
#pragma unroll
        for (int k = 0; k < 27; ++k) lds[wid][k] = s[k];
    __syncthreads();

    if (threadIdx.x < 27) {
        const int k = threadIdx.x;
        const float v = lds[0][k] + lds[1][k] + lds[2][k] + lds[3][k];
        atomicAdd(&acc[k], v);
    }
}

__global__ void pfn_finalize_kernel(const float* __restrict__ acc,
                                    const float* __restrict__ W,
                                    const float* __restrict__ b,
                                    const float* __restrict__ gamma,
                                    const float* __restrict__ beta,
                                    int n,
                                    float* __restrict__ Wp,
                                    float* __restrict__ bp) {
    int f = threadIdx.x;  // 64 threads
    double inv_n = 1.0 / (double)n;

    double mx[6];
#pragma unroll
    for (int j = 0; j < 6; ++j) mx[j] = (double)acc[j] * inv_n;

    double C[6][6];
    {
        int k = 0;
        for (int i = 0; i < 6; ++i)
            for (int j = i; j < 6; ++j) {
                double e = (double)acc[6 + k] * inv_n - mx[i] * mx[j];
                C[i][j] = e;
                C[j][i] = e;
                ++k;
            }
    }

    double w[6];
#pragma unroll
    for (int j = 0; j < 6; ++j) w[j] = (double)W[f * 6 + j];

    double mean_h = (double)b[f];
#pragma unroll
    for (int j = 0; j < 6; ++j) mean_h += w[j] * mx[j];

    double var_h = 0.0;
    for (int i = 0; i < 6; ++i) {
        double t = 0.0;
        for (int j = 0; j < 6; ++j) t += C[i][j] * w[j];
        var_h += w[i] * t;
    }

    double s = (double)gamma[f] / sqrt(var_h + BN_EPS);

#pragma unroll
    for (int j = 0; j < 6; ++j) Wp[f * 6 + j] = (float)(w[j] * s);
    bp[f] = (float)(((double)b[f] - mean_h) * s + (double)beta[f]);
}

// scanA: 256 blocks x 1024 entries. Writes intra-block exclusive scan to base[],
// per-block total to bsums[].
__global__ void __launch_bounds__(256)
pfn_scanA_kernel(const int* __restrict__ hist, int* __restrict__ base,
                 int* __restrict__ bsums) {
    const int tid = threadIdx.x;
    const int b = blockIdx.x;
    const int4 v = ((const int4*)(hist + b * 1024))[tid];
    const int t = v.x + v.y + v.z + v.w;

    __shared__ int sc[256];
    sc[tid] = t;
    __syncthreads();
#pragma unroll
    for (int off = 1; off < 256; off <<= 1) {
        const int add = (tid >= off) ? sc[tid - off] : 0;
        __syncthreads();
        sc[tid] += add;
        __syncthreads();
    }
    const int incl = sc[tid];
    const int excl = incl - t;

    int4 o;
    o.x = excl;
    o.y = o.x + v.x;
    o.z = o.y + v.y;
    o.w = o.z + v.z;
    ((int4*)(base + b * 1024))[tid] = o;
    if (tid == 255) bsums[b] = incl;
}

// scanB: exclusive scan of the 256 block sums, in place
__global__ void pfn_scanB_kernel(int* __restrict__ bsums) {
    const int tid = threadIdx.x;
    const int t = bsums[tid];
    __shared__ int sc[256];
    sc[tid] = t;
    __syncthreads();
#pragma unroll
    for (int off = 1; off < 256; off <<= 1) {
        const int add = (tid >= off) ? sc[tid - off] : 0;
        __syncthreads();
        sc[tid] += add;
        __syncthreads();
    }
    bsums[tid] = sc[tid] - t;  // exclusive
}

// scatter each point's 24B row into cell-sorted order
__global__ void __launch_bounds__(256)
pfn_scatter_sort_kernel(const float* __restrict__ x, const int* __restrict__ idx,
                        const int* __restrict__ bsums, int* __restrict__ base,
                        float* __restrict__ sx, int n) {
    const int p = blockIdx.x * blockDim.x + threadIdx.x;
    if (p >= n) return;
    const int2 ij = ((const int2*)idx)[p];
    const int cell = ij.x * N_PY + ij.y;
    const int pos = bsums[cell >> 10] + atomicAdd(&base[cell], 1);

    const float2* xp = (const float2*)(x + (size_t)p * 6);
    const float2 a = xp[0], b2 = xp[1], c = xp[2];
    float2* d = (float2*)(sx + (size_t)pos * 6);
    d[0] = a; d[1] = b2; d[2] = c;
}

// one wave per cell: stream the cell's contiguous segment of sorted_x,
// fold Linear+BN+ReLU, accumulate in registers, one 256B plain store.
__global__ void __launch_bounds__(256)
pfn_out_sorted_kernel(const float* __restrict__ sx,
                      const int* __restrict__ base, const int* __restrict__ hist,
                      const int* __restrict__ bsums,
                      const float* __restrict__ Wp, const float* __restrict__ bp,
                      float* __restrict__ out) {
    const int lane = threadIdx.x & 63;
    const int cell = __builtin_amdgcn_readfirstlane(
        (int)((blockIdx.x * blockDim.x + threadIdx.x) >> 6));

    const float w0 = Wp[lane * 6 + 0];
    const float w1 = Wp[lane * 6 + 1];
    const float w2 = Wp[lane * 6 + 2];
    const float w3 = Wp[lane * 6 + 3];
    const float w4 = Wp[lane * 6 + 4];
    const float w5 = Wp[lane * 6 + 5];
    const float bb = bp[lane];

    const int end = bsums[cell >> 10] + base[cell];  // base now holds local end
    const int cnt = hist[cell];

    float s = 0.f;
    for (int p = end - cnt; p < end; ++p) {
        const float* xp = sx + (size_t)p * 6;
        const float x0 = xp[0];
        const float x1 = xp[1];
        const float x2 = xp[2];
        const float x3 = xp[3];
        const float x4 = xp[4];
        const float x5 = xp[5];
        float v = bb;
        v = fmaf(w0, x0, v);
        v = fmaf(w1, x1, v);
        v = fmaf(w2, x2, v);
        v = fmaf(w3, x3, v);
        v = fmaf(w4, x4, v);
        v = fmaf(w5, x5, v);
        s += fmaxf(v, 0.0f);
    }
    out[(size_t)cell * OUT_F + lane] = s;  // coalesced 256B/wave, covers all cells
}

// ---- fallback (R3 linked-list path) if ws too small ----
__global__ void __launch_bounds__(256)
pfn_build_kernel(const int* __restrict__ idx, int n,
                 int* __restrict__ head, int* __restrict__ nxt) {
    const int p = blockIdx.x * blockDim.x + threadIdx.x;
    if (p >= n) return;
    const int2 ij = ((const int2*)idx)[p];
    const int cell = ij.x * N_PY + ij.y;
    nxt[p] = atomicExch(&head[cell], p);
}

__global__ void __launch_bounds__(256)
pfn_output_kernel(const float* __restrict__ x,
                  const int* __restrict__ head,
                  const int* __restrict__ nxt,
                  const float* __restrict__ Wp,
                  const float* __restrict__ bp,
                  float* __restrict__ out) {
    const int lane = threadIdx.x & 63;
    const int cell = __builtin_amdgcn_readfirstlane(
        (int)((blockIdx.x * blockDim.x + threadIdx.x) >> 6));

    const float w0 = Wp[lane * 6 + 0];
    const float w1 = Wp[lane * 6 + 1];
    const float w2 = Wp[lane * 6 + 2];
    const float w3 = Wp[lane * 6 + 3];
    const float w4 = Wp[lane * 6 + 4];
    const float w5 = Wp[lane * 6 + 5];
    const float bb = bp[lane];

    float s = 0.f;
    int p = head[cell];
    while (p >= 0) {
        const float* xp = x + (size_t)p * 6;
        const int pn = nxt[p];
        const float x0 = xp[0];
        const float x1 = xp[1];
        const float x2 = xp[2];
        const float x3 = xp[3];
        const float x4 = xp[4];
        const float x5 = xp[5];
        float v = bb;
        v = fmaf(w0, x0, v);
        v = fmaf(w1, x1, v);
        v = fmaf(w2, x2, v);
        v = fmaf(w3, x3, v);
        v = fmaf(w4, x4, v);
        v = fmaf(w5, x5, v);
        s += fmaxf(v, 0.0f);
        p = pn;
    }
    out[(size_t)cell * OUT_F + lane] = s;
}

extern "C" void kernel_launch(void* const* d_in, const int* in_sizes, int n_in,
                              void* d_out, int out_size, void* d_ws, size_t ws_size,
                              hipStream_t stream) {
    const float* x     = (const float*)d_in[0];
    const int*   idx   = (const int*)d_in[1];
    const float* W     = (const float*)d_in[2];
    const float* b     = (const float*)d_in[3];
    const float* gamma = (const float*)d_in[4];
    const float* beta  = (const float*)d_in[5];
    float* out = (float*)d_out;

    const int n = in_sizes[0] / IN_F;

    float* acc = (float*)d_ws;
    float* Wp  = (float*)((char*)d_ws + 512);
    float* bp  = Wp + OUT_F * IN_F;

    int*   hist  = (int*)((char*)d_ws + 4096);
    int*   base  = hist + N_CELLS;
    int*   bsums = base + N_CELLS;
    float* sx    = (float*)((char*)(bsums + 1024));  // 4KB pad for bsums

    const size_t need_sorted =
        4096 + (size_t)N_CELLS * 8 + 4096 + (size_t)n * IN_F * sizeof(float);

    if (ws_size >= need_sorted) {
        // zero acc (512B) + hist (1MB) in one memset; Wp/bp recomputed after
        hipMemsetAsync(d_ws, 0, 4096 + (size_t)N_CELLS * sizeof(int), stream);
        pfn_stats_hist_kernel<<<512, 256, 0, stream>>>(x, idx, n, acc, hist);
        pfn_finalize_kernel<<<1, 64, 0, stream>>>(acc, W, b, gamma, beta, n, Wp, bp);
        pfn_scanA_kernel<<<N_CELLS / 1024, 256, 0, stream>>>(hist, base, bsums);
        pfn_scanB_kernel<<<1, 256, 0, stream>>>(bsums);
        pfn_scatter_sort_kernel<<<(n + 255) / 256, 256, 0, stream>>>(
            x, idx, bsums, base, sx, n);
        pfn_out_sorted_kernel<<<N_CELLS / 4, 256, 0, stream>>>(
            sx, base, hist, bsums, Wp, bp, out);
    } else {
        // linked-list fallback
        int* head = (int*)((char*)d_ws + 4096);
        int* nxt  = head + N_CELLS;
        hipMemsetAsync(d_ws, 0, 512, stream);
        pfn_stats_hist_kernel<<<512, 256, 0, stream>>>(x, idx, n, acc, head);
        // head was used as hist scratch; reset to -1 for list build
        hipMemsetAsync(head, 0xFF, (size_t)N_CELLS * sizeof(int), stream);
        pfn_finalize_kernel<<<1, 64, 0, stream>>>(acc, W, b, gamma, beta, n, Wp, bp);
        pfn_build_kernel<<<(n + 255) / 256, 256, 0, stream>>>(idx, n, head, nxt);
        pfn_output_kernel<<<N_CELLS / 4, 256, 0, stream>>>(x, head, nxt, Wp, bp, out);
    }
}